// Round 3
// baseline (585.295 us; speedup 1.0000x reference)
//
#include <hip/hip_runtime.h>
#include <cstdint>
#include <cstddef>

#define N_TOK 8192
#define DIM   1024
#define NEXP  8
#define HID   2816
#define CAP   1280   // int(1.25 * 8192 / 8)

typedef __bf16 bf16x8 __attribute__((ext_vector_type(8)));
typedef float  floatx4 __attribute__((ext_vector_type(4)));
typedef unsigned short u16x8 __attribute__((ext_vector_type(8)));

__device__ __forceinline__ unsigned short f2bf(float f) {
  return __builtin_bit_cast(unsigned short, (__bf16)f);
}

// async global->LDS, 16B per lane. LDS dest must be wave-uniform base + lane*16.
__device__ __forceinline__ void async16(void* lds, const void* g) {
  __builtin_amdgcn_global_load_lds(
      (const __attribute__((address_space(1))) void*)g,
      (__attribute__((address_space(3))) void*)lds, 16, 0, 0);
}

// ---------------------------------------------------------------------------
// Routing: FCFS position per expert queue. One block, 256 thr, 32 tok/thread.
// Register histograms via compare-add (no dynamic reg indexing -> no scratch),
// shuffle-based parallel scan (wave w scans experts 2w, 2w+1).
// ---------------------------------------------------------------------------
__global__ __launch_bounds__(256)
void route_kernel(const int* __restrict__ idx, int idx_stride,
                  int* __restrict__ slot,
                  int* __restrict__ slot_token,
                  int* __restrict__ counts) {
  __shared__ int hist[256][9];   // padded: bank = (9t+e)%32, conflict-free-ish
  const int t = threadIdx.x;

  int myidx[32];
  if (idx_stride == 1) {
    const int4* p = (const int4*)(idx + (size_t)t * 32);
#pragma unroll
    for (int i = 0; i < 8; i++) {
      const int4 v = p[i];
      myidx[4 * i + 0] = v.x; myidx[4 * i + 1] = v.y;
      myidx[4 * i + 2] = v.z; myidx[4 * i + 3] = v.w;
    }
  } else {  // int64 exposed as int32 pairs, little-endian low word
    const int4* p = (const int4*)(idx + (size_t)t * 64);
#pragma unroll
    for (int i = 0; i < 16; i++) {
      const int4 v = p[i];
      myidx[2 * i + 0] = v.x; myidx[2 * i + 1] = v.z;
    }
  }

  int c[NEXP];
#pragma unroll
  for (int k = 0; k < NEXP; k++) c[k] = 0;
#pragma unroll
  for (int i = 0; i < 32; i++) {
    const int e = myidx[i];
#pragma unroll
    for (int k = 0; k < NEXP; k++) c[k] += (e == k);
  }
#pragma unroll
  for (int k = 0; k < NEXP; k++) hist[t][k] = c[k];
  __syncthreads();

  // scan: wave w handles experts 2w and 2w+1; lane l owns rows 4l..4l+3
  const int lane = t & 63;
  const int w = t >> 6;
#pragma unroll
  for (int which = 0; which < 2; which++) {
    const int e = w * 2 + which;
    int v[4], s = 0;
#pragma unroll
    for (int i = 0; i < 4; i++) { v[i] = hist[lane * 4 + i][e]; s += v[i]; }
    int x = s;
#pragma unroll
    for (int d = 1; d < 64; d <<= 1) {
      const int n = __shfl_up(x, d, 64);
      if (lane >= d) x += n;
    }
    int run = x - s;  // exclusive prefix of this lane's group
#pragma unroll
    for (int i = 0; i < 4; i++) { const int tmp = v[i]; hist[lane * 4 + i][e] = run; run += tmp; }
    if (lane == 63) counts[e] = run < CAP ? run : CAP;
  }
  __syncthreads();

  int b[NEXP];
#pragma unroll
  for (int k = 0; k < NEXP; k++) b[k] = hist[t][k];
  for (int i = 0; i < 32; i++) {
    const int e = myidx[i];
    int p = 0;
#pragma unroll
    for (int k = 0; k < NEXP; k++) p += (e == k) ? b[k] : 0;
    const int n = t * 32 + i;
    if (p < CAP) {
      const int s2 = e * CAP + p;
      slot[n] = s2;
      slot_token[s2] = n;
    } else {
      slot[n] = -1;
    }
#pragma unroll
    for (int k = 0; k < NEXP; k++) b[k] += (e == k);
  }
}

// ---------------------------------------------------------------------------
// Dispatch: kept tokens -> bf16 xe[slot]; dropped tokens -> y = x (fp32).
// ---------------------------------------------------------------------------
__global__ void dispatch_kernel(const float* __restrict__ x,
                                const int* __restrict__ slot,
                                unsigned short* __restrict__ xe,
                                float* __restrict__ y) {
  const int n = blockIdx.x;
  const int t = threadIdx.x;
  const int s = slot[n];
  const float4 v = ((const float4*)(x + (size_t)n * DIM))[t];
  if (s >= 0) {
    ushort4 b;
    b.x = f2bf(v.x); b.y = f2bf(v.y); b.z = f2bf(v.z); b.w = f2bf(v.w);
    ((ushort4*)(xe + (size_t)s * DIM))[t] = b;
  } else {
    ((float4*)(y + (size_t)n * DIM))[t] = v;
  }
}

// ---------------------------------------------------------------------------
// Fused transpose+cvt for all 3 weight tensors: [E][R][C] fp32 -> [E][C][R]
// bf16. 64x64 tiles; float4 coalesced loads; 16B stores, 128B contiguous per
// 8 lanes. LDS [64][65]: both phases <=2-way bank aliasing (free).
// grid: (704, 3, 8)  — y = tensor, z = expert.
// ---------------------------------------------------------------------------
__global__ __launch_bounds__(256)
void transpose_cvt_all(const float* __restrict__ Wg, const float* __restrict__ Wu,
                       const float* __restrict__ Wd,
                       unsigned short* __restrict__ wg_t,
                       unsigned short* __restrict__ wu_t,
                       unsigned short* __restrict__ wd_t) {
  __shared__ float tile[64][65];
  const int mat = blockIdx.y, e = blockIdx.z, tid = blockIdx.x;
  const float* in;
  unsigned short* outp;
  int R, C;
  if (mat == 0)      { in = Wg; outp = wg_t; R = DIM; C = HID; }
  else if (mat == 1) { in = Wu; outp = wu_t; R = DIM; C = HID; }
  else               { in = Wd; outp = wd_t; R = HID; C = DIM; }
  const int tilesC = C / 64;
  const int r0 = (tid / tilesC) * 64, c0 = (tid % tilesC) * 64;
  const float* ib = in + (size_t)e * R * C;
  unsigned short* ob = outp + (size_t)e * R * C;
  const int t = threadIdx.x;

  const int lr = t >> 4;          // 0..15
  const int lc = (t & 15) * 4;    // 0..60
#pragma unroll
  for (int i = 0; i < 4; i++) {
    const float4 v = *(const float4*)(ib + (size_t)(r0 + lr + i * 16) * C + c0 + lc);
    tile[lr + i * 16][lc + 0] = v.x;
    tile[lr + i * 16][lc + 1] = v.y;
    tile[lr + i * 16][lc + 2] = v.z;
    tile[lr + i * 16][lc + 3] = v.w;
  }
  __syncthreads();
  const int chunk = t & 7;        // 8 chunks x 16B = 128B contiguous per row
#pragma unroll
  for (int h = 0; h < 2; h++) {
    const int row = (t >> 3) + 32 * h;  // output row = original column
    u16x8 o;
#pragma unroll
    for (int j = 0; j < 8; j++) o[j] = f2bf(tile[chunk * 8 + j][row]);
    *(u16x8*)(ob + (size_t)(c0 + row) * R + r0 + chunk * 8) = o;
  }
}

// ---------------------------------------------------------------------------
// Fused gate+up grouped GEMM. Tile 128M x 64N (x2 matrices), BK=64.
// A [E][CAP][d] bf16 K-major; Bg/Bu [E][h][d] bf16 K-major.
// LDS rows = 128B (8 chunks of 16B), chunk XOR-swizzle c ^ (row&7): every
// 8-lane phase of a ds_read_b128 tiles all 32 banks -> conflict-free.
// 1-D grid, XCD-aware decode. Epilogue: hact = silu(g)*u bf16.
// ---------------------------------------------------------------------------
__global__ __launch_bounds__(256)
void gateup_gemm(const unsigned short* __restrict__ A,
                 const unsigned short* __restrict__ Bg,
                 const unsigned short* __restrict__ Bu,
                 const int* __restrict__ counts,
                 unsigned short* __restrict__ hact) {
  const int bid = blockIdx.x;
  const int xcd = bid & 7;
  const int slotb = bid >> 3;      // 0..439
  const int m = slotb % 10;
  const int cgl = slotb / 10;      // 0..43
  const int cg = xcd + 8 * cgl;    // 0..351
  const int n = cg % 44;
  const int e = cg / 44;

  const int cnt = counts[e];
  const int m0 = m * 128;
  if (m0 >= cnt) return;
  const int n0 = n * 64;

  __shared__ char smem[32768];     // A 16K | Bg 8K | Bu 8K
  char* const lA  = smem;
  char* const lBg = smem + 16384;
  char* const lBu = smem + 24576;

  const int t = threadIdx.x;
  const int lane = t & 63;
  const int w = t >> 6;
  const int wr = w >> 1;
  const int wc = w & 1;

  // staging: chunk index g = r*256 + t; row = g>>3, LDS chunk pos = t&7,
  // global source chunk = (t&7) ^ ((t>>3)&7)  (XOR swizzle, self-inverse)
  const int srow = t >> 3;                    // 0..31 per rep
  const int schk = (t & 7) ^ (srow & 7);      // swizzled source chunk
  const unsigned short* aP[4];
  const unsigned short* bgP[2];
  const unsigned short* buP[2];
#pragma unroll
  for (int r = 0; r < 4; r++)
    aP[r] = A + (size_t)e * CAP * DIM + (size_t)(m0 + r * 32 + srow) * DIM + schk * 8;
#pragma unroll
  for (int r = 0; r < 2; r++) {
    bgP[r] = Bg + (size_t)e * HID * DIM + (size_t)(n0 + r * 32 + srow) * DIM + schk * 8;
    buP[r] = Bu + (size_t)e * HID * DIM + (size_t)(n0 + r * 32 + srow) * DIM + schk * 8;
  }

  floatx4 accg[4][2] = {};
  floatx4 accu[4][2] = {};

  const int cl = lane & 15;
  const int quad = lane >> 4;
  const int x0 = quad ^ (lane & 7);      // chunk pos for ks=0 (c_log=quad)
  const int x1 = x0 ^ 4;                 // ks=1 (c_log=4|quad)
  const int mrB = (wr * 64 + cl) * 128;  // A frag row base (bytes)
  const int ncB = (wc * 32 + cl) * 128;  // B frag row base (bytes)

  for (int kk = 0; kk < DIM; kk += 64) {
#pragma unroll
    for (int r = 0; r < 4; r++) async16(lA + r * 4096 + t * 16, aP[r]);
#pragma unroll
    for (int r = 0; r < 2; r++) {
      async16(lBg + r * 4096 + t * 16, bgP[r]);
      async16(lBu + r * 4096 + t * 16, buP[r]);
    }
#pragma unroll
    for (int r = 0; r < 4; r++) aP[r] += 64;
#pragma unroll
    for (int r = 0; r < 2; r++) { bgP[r] += 64; buP[r] += 64; }
    __syncthreads();
#pragma unroll
    for (int ks = 0; ks < 2; ks++) {
      const int x = ks ? x1 : x0;
      bf16x8 af[4], gf[2], uf[2];
#pragma unroll
      for (int mi = 0; mi < 4; mi++)
        af[mi] = *(const bf16x8*)(lA + mrB + mi * 2048 + x * 16);
#pragma unroll
      for (int ni = 0; ni < 2; ni++) {
        gf[ni] = *(const bf16x8*)(lBg + ncB + ni * 2048 + x * 16);
        uf[ni] = *(const bf16x8*)(lBu + ncB + ni * 2048 + x * 16);
      }
#pragma unroll
      for (int mi = 0; mi < 4; mi++)
#pragma unroll
        for (int ni = 0; ni < 2; ni++) {
          accg[mi][ni] = __builtin_amdgcn_mfma_f32_16x16x32_bf16(
              af[mi], gf[ni], accg[mi][ni], 0, 0, 0);
          accu[mi][ni] = __builtin_amdgcn_mfma_f32_16x16x32_bf16(
              af[mi], uf[ni], accu[mi][ni], 0, 0, 0);
        }
    }
    __syncthreads();
  }

  // C/D layout: col = lane&15, row = quad*4 + reg
  unsigned short* ob = hact + (size_t)e * CAP * HID;
#pragma unroll
  for (int mi = 0; mi < 4; mi++)
#pragma unroll
    for (int r = 0; r < 4; r++) {
      const int row = m0 + wr * 64 + mi * 16 + quad * 4 + r;
      const size_t rb = (size_t)row * HID;
#pragma unroll
      for (int ni = 0; ni < 2; ni++) {
        const int col = n0 + wc * 32 + ni * 16 + cl;
        const float g = accg[mi][ni][r];
        const float u = accu[mi][ni][r];
        ob[rb + col] = f2bf(g / (1.0f + __expf(-g)) * u);
      }
    }
}

// ---------------------------------------------------------------------------
// Down GEMM + fused gather/scale. Tile 128x128, BK=64. A = hact [E][CAP][h],
// Bt = Wd^T [E][d][h]. Epilogue: y[slot_token[row]] = acc*score (row<cnt).
// ---------------------------------------------------------------------------
__global__ __launch_bounds__(256)
void down_gemm(const unsigned short* __restrict__ A,
               const unsigned short* __restrict__ Bt,
               const int* __restrict__ counts,
               const int* __restrict__ slot_token,
               const float* __restrict__ scores,
               float* __restrict__ y) {
  const int bid = blockIdx.x;
  const int xcd = bid & 7;
  const int slotb = bid >> 3;      // 0..79
  const int m = slotb % 10;
  const int cgl = slotb / 10;      // 0..7
  const int cg = xcd + 8 * cgl;    // 0..63
  const int n = cg % 8;
  const int e = cg / 8;

  const int cnt = counts[e];
  const int m0 = m * 128;
  if (m0 >= cnt) return;
  const int n0 = n * 128;

  __shared__ char smem[32768];     // A 16K | B 16K
  char* const lA = smem;
  char* const lB = smem + 16384;

  const int t = threadIdx.x;
  const int lane = t & 63;
  const int w = t >> 6;
  const int wr = w >> 1;
  const int wc = w & 1;

  const int srow = t >> 3;
  const int schk = (t & 7) ^ (srow & 7);
  const unsigned short* aP[4];
  const unsigned short* bP[4];
#pragma unroll
  for (int r = 0; r < 4; r++) {
    aP[r] = A  + (size_t)e * CAP * HID + (size_t)(m0 + r * 32 + srow) * HID + schk * 8;
    bP[r] = Bt + (size_t)e * DIM * HID + (size_t)(n0 + r * 32 + srow) * HID + schk * 8;
  }

  floatx4 acc[4][4] = {};

  const int cl = lane & 15;
  const int quad = lane >> 4;
  const int x0 = quad ^ (lane & 7);
  const int x1 = x0 ^ 4;
  const int mrB = (wr * 64 + cl) * 128;
  const int ncB = (wc * 64 + cl) * 128;

  for (int kk = 0; kk < HID; kk += 64) {
#pragma unroll
    for (int r = 0; r < 4; r++) {
      async16(lA + r * 4096 + t * 16, aP[r]);
      async16(lB + r * 4096 + t * 16, bP[r]);
      aP[r] += 64; bP[r] += 64;
    }
    __syncthreads();
#pragma unroll
    for (int ks = 0; ks < 2; ks++) {
      const int x = ks ? x1 : x0;
      bf16x8 af[4], bfr[4];
#pragma unroll
      for (int mi = 0; mi < 4; mi++)
        af[mi] = *(const bf16x8*)(lA + mrB + mi * 2048 + x * 16);
#pragma unroll
      for (int ni = 0; ni < 4; ni++)
        bfr[ni] = *(const bf16x8*)(lB + ncB + ni * 2048 + x * 16);
#pragma unroll
      for (int mi = 0; mi < 4; mi++)
#pragma unroll
        for (int ni = 0; ni < 4; ni++)
          acc[mi][ni] = __builtin_amdgcn_mfma_f32_16x16x32_bf16(
              af[mi], bfr[ni], acc[mi][ni], 0, 0, 0);
    }
    __syncthreads();
  }

  const int clc = lane & 15;
#pragma unroll
  for (int mi = 0; mi < 4; mi++)
#pragma unroll
    for (int r = 0; r < 4; r++) {
      const int row = m0 + wr * 64 + mi * 16 + quad * 4 + r;
      if (row < cnt) {
        const int tok = slot_token[e * CAP + row];
        const float s = scores[tok];
        float* yr = y + (size_t)tok * DIM;
#pragma unroll
        for (int ni = 0; ni < 4; ni++) {
          const int col = n0 + wc * 64 + ni * 16 + clc;
          yr[col] = acc[mi][ni][r] * s;
        }
      }
    }
}

extern "C" void kernel_launch(void* const* d_in, const int* in_sizes, int n_in,
                              void* d_out, int out_size, void* d_ws, size_t ws_size,
                              hipStream_t stream) {
  const float* x      = (const float*)d_in[0];
  const int*   idx    = (const int*)d_in[1];
  const float* scores = (const float*)d_in[2];
  const float* Wg     = (const float*)d_in[3];
  const float* Wu     = (const float*)d_in[4];
  const float* Wd     = (const float*)d_in[5];
  float* y = (float*)d_out;

  const int idx_stride = (in_sizes[1] == 2 * N_TOK) ? 2 : 1;

  char* ws = (char*)d_ws;
  size_t off = 0;
  auto alloc = [&](size_t b) -> char* {
    char* p = ws + off;
    off += (b + 255) & ~(size_t)255;
    return p;
  };
  int* counts            = (int*)alloc(NEXP * 4);
  int* slot              = (int*)alloc((size_t)N_TOK * 4);
  int* slot_token        = (int*)alloc((size_t)NEXP * CAP * 4);
  unsigned short* xe     = (unsigned short*)alloc((size_t)NEXP * CAP * DIM * 2);
  unsigned short* hact   = (unsigned short*)alloc((size_t)NEXP * CAP * HID * 2);
  unsigned short* wg_t   = (unsigned short*)alloc((size_t)NEXP * DIM * HID * 2);
  unsigned short* wu_t   = (unsigned short*)alloc((size_t)NEXP * DIM * HID * 2);
  unsigned short* wd_t   = (unsigned short*)alloc((size_t)NEXP * DIM * HID * 2);
  (void)ws_size; (void)n_in; (void)out_size;

  route_kernel<<<1, 256, 0, stream>>>(idx, idx_stride, slot, slot_token, counts);
  dispatch_kernel<<<N_TOK, 256, 0, stream>>>(x, slot, xe, y);

  // all three weight tensors: [R][C] fp32 -> [C][R] bf16
  transpose_cvt_all<<<dim3(704, 3, NEXP), 256, 0, stream>>>(Wg, Wu, Wd, wg_t, wu_t, wd_t);

  // fused gate+up: hact = silu(xe@Wg) * (xe@Wu)
  gateup_gemm<<<8 * 44 * 10, 256, 0, stream>>>(xe, wg_t, wu_t, counts, hact);
  // down + fused gather/scale: y[tok] = (hact @ Wd) * score
  down_gemm<<<8 * 8 * 10, 256, 0, stream>>>(hact, wd_t, counts, slot_token, scores, y);
}